// Round 10
// baseline (179.010 us; speedup 1.0000x reference)
//
#include <hip/hip_runtime.h>
#include <math.h>

typedef unsigned int u32;
typedef unsigned long long u64;

#define B 8
#define H 1024
#define W 1536
#define NPIX (H * W)
#define NK 2048
#define BORDER 16
#define NSEG 64
#define TY 8
#define NTILE 6            // W / 256
#define GRIDY 31           // 992 rows / (TY * 4 waves)
#define HBINS 512
#define TOPK_CAP 4096
#define SEG_CAP_MAX 4096
#define CTR_PAD 32
#define IDX_MASK 0x1FFFFFu

// workspace layout (bytes) — [0, OFF_CAND) is zeroed by one memset
#define OFF_TCOUNT 128      // u32[B*CTR_PAD]            ends 1152
#define OFF_HIST   4096     // u32[B*HBINS]              ends 20480
#define OFF_SEGCNT 20480    // u32[B*NSEG*CTR_PAD]       ends 86016
#define OFF_RANK   86016    // u32[B*TOPK_CAP]           ends 217088
#define OFF_KEYS   217088   // u64[B*TOPK_CAP]           ends 479232
#define OFF_CAND   479232   // u32[B*NSEG*seg_cap]  (disjoint from keys!)

// launch_bounds(256, 4): 4 waves/EU -> ~128 VGPR budget so the 18-row
// preload burst stays fully in flight (at default the compiler picked
// 36 VGPRs and serialized the loads -> latency-bound at 2.2 TB/s).
__global__ __launch_bounds__(256, 4) void cand_k(const float* __restrict__ neur,
                                              const float* __restrict__ score,
                                              u32* __restrict__ candp,
                                              u32* __restrict__ segcnt,
                                              u32* __restrict__ hist, int seg_cap) {
    __shared__ u32 lh[HBINS];
    int tile = blockIdx.x;
    int b = blockIdx.z;
    int wave = threadIdx.x >> 6;
    int lane = threadIdx.x & 63;
    for (int i = threadIdx.x; i < HBINS; i += 256) lh[i] = 0;
    __syncthreads();

    int strip = blockIdx.y * 4 + wave;
    int y0 = BORDER + strip * TY;
    int x0 = tile * 256 + lane * 4;
    const float* s = score + (size_t)b * NPIX;
    const float* nb = neur + (size_t)b * NPIX;
    bool haveL = (tile > 0) && (lane == 0);
    bool haveR = (tile < NTILE - 1) && (lane == 63);

    // preload: 10 score rows + 8 neur rows, all independent (one vmcnt burst)
    float4 rv[TY + 2];
    float4 nvv[TY];
    float le[TY + 2], re[TY + 2];
    const float* base_row = s + (size_t)(y0 - 1) * W + x0;
    const float* nrow = nb + (size_t)y0 * W + x0;
    #pragma unroll
    for (int r = 0; r < TY + 2; ++r) rv[r] = *(const float4*)(base_row + (size_t)r * W);
    #pragma unroll
    for (int r = 0; r < TY; ++r) nvv[r] = *(const float4*)(nrow + (size_t)r * W);
    #pragma unroll
    for (int r = 0; r < TY + 2; ++r) {
        le[r] = haveL ? base_row[(size_t)r * W - 1] : 0.0f;
        re[r] = haveR ? base_row[(size_t)r * W + 4] : 0.0f;
    }

    bool xok[4];
    #pragma unroll
    for (int e = 0; e < 4; ++e) {
        int x = x0 + e;
        xok[e] = (x >= BORDER) && (x < W - BORDER);
    }

    // phase A: pure register compute of all ext bits
    u32 extbits = 0;
    {
        float4 hm, h0, hp;
        #pragma unroll
        for (int r = 0; r < 2; ++r) {
            float4 c = rv[r];
            float l = __shfl_up(c.w, 1); if (haveL) l = le[r];
            float rr = __shfl_down(c.x, 1); if (haveR) rr = re[r];
            float4 hh;
            hh.x = fmaxf(fmaxf(l, c.x), c.y);
            hh.y = fmaxf(fmaxf(c.x, c.y), c.z);
            hh.z = fmaxf(fmaxf(c.y, c.z), c.w);
            hh.w = fmaxf(fmaxf(c.z, c.w), rr);
            if (r == 0) hm = hh; else h0 = hh;
        }
        #pragma unroll
        for (int ys = 0; ys < TY; ++ys) {
            float4 c = rv[ys + 2];
            float l = __shfl_up(c.w, 1); if (haveL) l = le[ys + 2];
            float rr = __shfl_down(c.x, 1); if (haveR) rr = re[ys + 2];
            hp.x = fmaxf(fmaxf(l, c.x), c.y);
            hp.y = fmaxf(fmaxf(c.x, c.y), c.z);
            hp.z = fmaxf(fmaxf(c.y, c.z), c.w);
            hp.w = fmaxf(fmaxf(c.z, c.w), rr);
            float pv[4];
            pv[0] = fmaxf(fmaxf(hm.x, h0.x), hp.x);
            pv[1] = fmaxf(fmaxf(hm.y, h0.y), hp.y);
            pv[2] = fmaxf(fmaxf(hm.z, h0.z), hp.z);
            pv[3] = fmaxf(fmaxf(hm.w, h0.w), hp.w);
            float4 c0 = rv[ys + 1];
            float cv[4] = {c0.x, c0.y, c0.z, c0.w};
            #pragma unroll
            for (int e = 0; e < 4; ++e)
                if (xok[e] && cv[e] >= pv[e]) extbits |= (1u << (ys * 4 + e));
            hm = h0; h0 = hp;
        }
    }

    // phase B: one wave scan + one leader atomic; nv already in registers
    u32 c = (u32)__popc(extbits);
    u32 scan = c;
    #pragma unroll
    for (int off = 1; off < 64; off <<= 1) {
        u32 o = (u32)__shfl_up((int)scan, off, 64);
        if (lane >= off) scan += o;
    }
    u32 excl = scan - c;
    u32 tot = (u32)__shfl((int)scan, 63, 64);
    if (tot) {
        int seg = (strip * NTILE + tile) & (NSEG - 1);
        u32* ctr = &segcnt[(u32)(b * NSEG + seg) * CTR_PAD];
        u32 base = 0;
        if (lane == 63) base = atomicAdd(ctr, scan);
        base = (u32)__shfl((int)base, 63, 64);
        u32 pos0 = base + excl;
        u32 sbase = (u32)(b * NSEG + seg) * (u32)seg_cap;
        u32 idxbase = (u32)(y0 * W + x0);
        #pragma unroll
        for (int k = 0; k < 32; ++k) {
            if (extbits & (1u << k)) {
                const int ro = k >> 2, e = k & 3;
                float4 nq = nvv[ro];
                float raw = (e == 0) ? nq.x : (e == 1) ? nq.y : (e == 2) ? nq.z : nq.w;
                float nv = fmaxf(raw, 0.0f);
                u32 fb = __float_as_uint(nv);
                u32 bin = fb >> 21; if (bin > HBINS - 1) bin = HBINS - 1;
                atomicAdd(&lh[bin], 1u);
                u32 idx = idxbase + (u32)ro * W + (u32)e;
                u32 p = pos0 + (u32)__popc(extbits & ((1u << k) - 1u));
                if ((int)p < seg_cap) candp[sbase + p] = (bin << 21) | idx;
            }
        }
    }
    __syncthreads();
    for (int i = threadIdx.x; i < HBINS; i += 256) {
        u32 v = lh[i];
        if (v) atomicAdd(&hist[(u32)b * HBINS + i], v);
    }
}

__global__ __launch_bounds__(256) void compact_k(const u32* __restrict__ candp,
                                                 const u32* __restrict__ segcnt,
                                                 const u32* __restrict__ hist,
                                                 const float* __restrict__ neur,
                                                 u64* __restrict__ keysout,
                                                 u32* tcount, int seg_cap) {
    __shared__ u32 piv_s;
    int seg = blockIdx.x;
    int b = blockIdx.y;
    int lane = threadIdx.x & 63;
    // wave 0: recompute pivot from hist (512 bins, 8/lane + shfl scan)
    if (threadIdx.x < 64) {
        if (threadIdx.x == 0) piv_s = 0xFFFFFFFFu;
        u32 v[8];
        u32 s8 = 0;
        #pragma unroll
        for (int e = 0; e < 8; ++e) {
            v[e] = hist[(u32)b * HBINS + (u32)threadIdx.x * 8u + e];
            s8 += v[e];
        }
        u32 incl = s8;
        #pragma unroll
        for (int off = 1; off < 64; off <<= 1) {
            u32 o = (u32)__shfl_up((int)incl, off, 64);
            if (lane >= off) incl += o;
        }
        u32 excl = incl - s8;
        if (excl < NK && incl >= NK) {
            u32 cum = excl;
            u32 T = 0;
            #pragma unroll
            for (int e = 0; e < 8; ++e) {
                cum += v[e];
                if (cum >= NK) { T = (u32)threadIdx.x * 8u + e; break; }
            }
            piv_s = (T + 2u) << 21;  // include bins <= T+1 entirely
        }
    }
    __syncthreads();
    u32 piv = piv_s;
    const float* nb = neur + (size_t)b * NPIX;

    u32 cnt = segcnt[(u32)(b * NSEG + seg) * CTR_PAD];
    if ((int)cnt > seg_cap) cnt = (u32)seg_cap;
    u32 base = (u32)(b * NSEG + seg) * (u32)seg_cap;
    u32 iters = (cnt + 255u) / 256u;
    for (u32 it = 0; it < iters; ++it) {
        u32 i = it * 256u + threadIdx.x;
        bool f = false;
        u32 idx = 0;
        if (i < cnt) {
            u32 p = candp[base + i];
            f = (p < piv);
            idx = p & IDX_MASK;
        }
        u64 m = __ballot((int)f);
        if (m) {
            int leader = __ffsll((long long)m) - 1;
            u32 wbase = 0;
            if (lane == leader) wbase = atomicAdd(&tcount[b * CTR_PAD], (u32)__popcll(m));
            wbase = (u32)__shfl((int)wbase, leader, 64);
            if (f) {
                u32 pos = wbase + (u32)__popcll(m & ((1ull << (u32)lane) - 1ull));
                if (pos < TOPK_CAP) {
                    float nv = fmaxf(nb[idx], 0.0f);
                    float ness = (float)exp(-(double)nv);  // correctly-rounded f32 exp
                    keysout[(u32)b * TOPK_CAP + pos] =
                        ((u64)__float_as_uint(ness) << 32) | (u32)(~idx);
                }
            }
        }
    }
}

// exact descending rank: rank[i] = #{j : key_j > key_i}; keys distinct,
// zero-padded tail ranks >= cnt >= NK so never selected.
__global__ __launch_bounds__(1024) void rank_k(const u64* __restrict__ keys,
                                               u32* __restrict__ rank) {
    __shared__ u64 jk[1024];
    int b = blockIdx.z;
    u32 i = blockIdx.x * 1024u + threadIdx.x;
    u64 ki = keys[(u32)b * TOPK_CAP + i];
    jk[threadIdx.x] = keys[(u32)b * TOPK_CAP + blockIdx.y * 1024u + threadIdx.x];
    __syncthreads();
    u32 r = 0;
    #pragma unroll 8
    for (int j = 0; j < 1024; ++j) r += (jk[j] > ki) ? 1u : 0u;
    if (r) atomicAdd(&rank[(u32)b * TOPK_CAP + i], r);
}

__global__ __launch_bounds__(256) void refine_k(const float* __restrict__ neur,
                                                const float* __restrict__ score,
                                                const u64* __restrict__ keys,
                                                const u32* __restrict__ rank,
                                                float* __restrict__ out) {
    int b = blockIdx.y;
    u32 i = blockIdx.x * 256u + threadIdx.x;
    u32 r = rank[(u32)b * TOPK_CAP + i];
    if (r >= NK) return;
    const float* s = score + (size_t)b * NPIX;
    const float* nb = neur + (size_t)b * NPIX;
    u64 key = keys[(u32)b * TOPK_CAP + i];
    u32 idx = ~(u32)key;
    if (idx >= (u32)NPIX) return;  // defensive: never true for legitimate keys
    int y = (int)(idx / W), x = (int)(idx % W);
    int yc = min(max(y, 1), H - 2), xc = min(max(x, 1), W - 2);
    int p = yc * W + xc;
    float s00 = s[p], sp0 = s[p + W], sm0 = s[p - W], s0p = s[p + 1], s0m = s[p - 1];
    float spp = s[p + W + 1], spm = s[p + W - 1], smp = s[p - W + 1], smm = s[p - W - 1];
    float gy = 0.5f * (sp0 - sm0);
    float gx = 0.5f * (s0p - s0m);
    float hyy = sp0 - 2.0f * s00 + sm0;
    float hxx = s0p - 2.0f * s00 + s0m;
    float hxy = 0.25f * (spp - spm - smp + smm);
    float det = hyy * hxx - hxy * hxy;
    bool sing = fabsf(det) > 1e-12f;
    float sd = sing ? det : 1.0f;
    float iy = -(hxx * gy - hxy * gx) / sd;
    float ix = -(hyy * gx - hxy * gy) / sd;
    if (!sing) { iy = 0.0f; ix = 0.0f; }
    iy = fminf(fmaxf(iy, -0.5f), 0.5f);
    ix = fminf(fmaxf(ix, -0.5f), 0.5f);
    size_t o = ((size_t)b * NK + (size_t)r) * 3;
    out[o] = (float)y + 0.5f + iy;
    out[o + 1] = (float)x + 0.5f + ix;
    out[o + 2] = fmaxf(nb[idx], 0.0f);
}

extern "C" void kernel_launch(void* const* d_in, const int* in_sizes, int n_in,
                              void* d_out, int out_size, void* d_ws, size_t ws_size,
                              hipStream_t stream) {
    const float* neur = (const float*)d_in[0];
    const float* score = (const float*)d_in[1];
    float* out = (float*)d_out;
    char* ws = (char*)d_ws;
    u32* tcount = (u32*)(ws + OFF_TCOUNT);
    u32* hist = (u32*)(ws + OFF_HIST);
    u32* segcnt = (u32*)(ws + OFF_SEGCNT);
    u32* rank = (u32*)(ws + OFF_RANK);
    u64* keysbuf = (u64*)(ws + OFF_KEYS);
    u32* candp = (u32*)(ws + OFF_CAND);

    size_t avail = ws_size > OFF_CAND ? ws_size - OFF_CAND : 0;
    long long cap_ll = (long long)(avail / (4ull * B * NSEG));
    int seg_cap = cap_ll > SEG_CAP_MAX ? SEG_CAP_MAX : (int)cap_ll;

    // zero tcount/hist/segcnt/rank/keys in one memset node
    hipMemsetAsync(ws, 0, OFF_CAND, stream);
    cand_k<<<dim3(NTILE, GRIDY, B), 256, 0, stream>>>(neur, score, candp, segcnt, hist, seg_cap);
    compact_k<<<dim3(NSEG, B), 256, 0, stream>>>(candp, segcnt, hist, neur, keysbuf, tcount, seg_cap);
    rank_k<<<dim3(TOPK_CAP / 1024, TOPK_CAP / 1024, B), 1024, 0, stream>>>(keysbuf, rank);
    refine_k<<<dim3(TOPK_CAP / 256, B), 256, 0, stream>>>(neur, score, keysbuf, rank, out);
}